// Round 3
// baseline (608.040 us; speedup 1.0000x reference)
//
#include <hip/hip_runtime.h>
#include <math.h>

#define D 128
#define CHK 64
#define NCHUNK 128
#define LSEQ 8192
#define B_LR 0.005f
#define M_LR 0.01f

typedef float f2 __attribute__((ext_vector_type(2)));

template<int C>
__device__ __forceinline__ float dppx(float x){
  return __int_as_float(__builtin_amdgcn_update_dpp(0, __float_as_int(x), C, 0xF, 0xF, true));
}
__device__ __forceinline__ void pl32swap(float &a, float &b){ asm("v_permlane32_swap_b32 %0, %1" : "+v"(a), "+v"(b)); }
__device__ __forceinline__ void pl16swap(float &a, float &b){ asm("v_permlane16_swap_b32 %0, %1" : "+v"(a), "+v"(b)); }

// transpose-reduce: input a[64] per lane; lane L returns sum over all 64 lanes of a[L].
// (verified in rounds 1-2: absmax 0.0156)
__device__ __forceinline__ float butterfly64(float* a, int lane){
  #pragma unroll
  for (int t = 0; t < 32; ++t){ float u=a[t], w=a[t+32]; pl32swap(u,w); a[t]=u+w; }
  #pragma unroll
  for (int t = 0; t < 16; ++t){ float u=a[t], w=a[t+16]; pl16swap(u,w); a[t]=u+w; }
  const bool h8 = (lane & 8) != 0, h4 = (lane & 4) != 0, h2 = (lane & 2) != 0, h1 = (lane & 1) != 0;
  #pragma unroll
  for (int t = 0; t < 8; ++t){
    float send = h8 ? a[t] : a[t+8];
    float keep = h8 ? a[t+8] : a[t];
    a[t] = keep + dppx<0x128>(send);                  // row_ror:8 == lane^8
  }
  #pragma unroll
  for (int t = 0; t < 4; ++t){
    float send = h4 ? a[t] : a[t+4];
    float keep = h4 ? a[t+4] : a[t];
    a[t] = keep + __int_as_float(__builtin_amdgcn_ds_swizzle(__float_as_int(send), 0x101F)); // lane^4
  }
  #pragma unroll
  for (int t = 0; t < 2; ++t){
    float send = h2 ? a[t] : a[t+2];
    float keep = h2 ? a[t+2] : a[t];
    a[t] = keep + dppx<0x4E>(send);                   // quad_perm xor2
  }
  float send = h1 ? a[0] : a[1];
  float keep = h1 ? a[1] : a[0];
  return keep + dppx<0xB1>(send);                     // quad_perm xor1
}

__device__ __forceinline__ void gl_lds16(const float* g, float* l){
  __builtin_amdgcn_global_load_lds((const __attribute__((address_space(1))) float*)g,
                                   (__attribute__((address_space(3))) float*)l, 16, 0, 0);
}

__global__ __launch_bounds__(512, 1) void lfltm_fwd(
    const float* __restrict__ X,
    const float* __restrict__ init_mem,
    const float* __restrict__ init_opt,
    float* __restrict__ out)
{
  __shared__ float xs[2][CHK * D];       // 64 KiB: double-buffered x chunk, linear [c][j]
  __shared__ float outs[2][CHK * 9];     // out staging, pad 9 (2-way bank alias only)

  const int tid  = threadIdx.x;
  const int w    = tid >> 6;             // wave -> row within group
  const int lane = tid & 63;             // owns j = {2*lane, 2*lane+1}

  // XCD-aware: all blocks of one batch on one XCD (L2 reuse of X)
  const int bid  = blockIdx.x;
  const int xcd  = bid & 7;
  const int slot = bid >> 3;
  const int b    = xcd + 8 * (slot & 1);
  const int rg   = slot >> 1;
  const int i    = rg * 8 + w;

  const float* __restrict__ Xb = X + (size_t)b * (LSEQ * D);
  float* __restrict__ Ob       = out + (size_t)b * (LSEQ * D);

  // per-lane state: mem row pair + opt pair
  float m0 = init_mem[i * D + 2*lane];
  float m1 = init_mem[i * D + 2*lane + 1];
  float o0 = init_opt[i * D + 2*lane];
  float o1 = init_opt[i * D + 2*lane + 1];
  const float u0 = (2*lane     == i) ? 1.0f : 0.0f;   // delta_i fold: e-dot uses (m - e_i)
  const float u1 = (2*lane + 1 == i) ? 1.0f : 0.0f;

  // prologue: chunk 0 -> buf 0 (async direct-to-LDS)
  #pragma unroll
  for (int r = 0; r < 4; ++r)
    gl_lds16(Xb + (r*512 + tid)*4, &xs[0][(r*512 + tid)*4]);
  __syncthreads();

  for (int ch = 0; ch < NCHUNK; ++ch) {
    const int cur = ch & 1;

    // (a) coalesced store of previous chunk's outputs
    if (ch > 0) {
      const int c = tid >> 3, ww = tid & 7;
      Ob[(size_t)((ch-1)*CHK + c)*D + rg*8 + ww] = outs[cur ^ 1][c*9 + ww];
    }

    // (b) prefetch next chunk -> other buffer (in flight across whole compute)
    {
      int chn = ch + 1; if (chn >= NCHUNK) chn = NCHUNK - 1;
      const float* gb = Xb + (size_t)chn * (CHK * D);
      #pragma unroll
      for (int r = 0; r < 4; ++r)
        gl_lds16(gb + (r*512 + tid)*4, &xs[cur ^ 1][(r*512 + tid)*4]);
    }

    // (c) x[token=lane, i] gather from global (VMEM idle; L2-hot)
    const float xci = Xb[(size_t)(ch*CHK + lane)*D + i];

    const float lr0 = 1.0f / (1.0f + __expf(-o0));
    const float lr1 = 1.0f / (1.0f + __expf(-o1));
    const float mp0 = m0 - u0;
    const float mp1 = m1 - u1;

    // (d) read own column-pair ONCE into registers, pin with keep-alive asm
    f2 xr[CHK];
    const float* xb = &xs[cur][2*lane];
    #pragma unroll
    for (int c = 0; c < CHK; ++c)
      xr[c] = *(const f2*)(xb + c*D);
    #pragma unroll
    for (int c = 0; c < CHK; ++c)
      asm volatile("" : "+v"(xr[c]));            // defeat LDS-load rematerialization

    // (e) pass 1: partial dots -> butterfly => lane c holds e_c
    float arr[CHK];
    #pragma unroll
    for (int c = 0; c < CHK; ++c)
      arr[c] = fmaf(mp1, xr[c].y, mp0 * xr[c].x);
    const float e_own = butterfly64(arr, lane);

    // (f) sequential token march — pure scalar, e_t via readlane (SGPR broadcast)
    float S0 = 0.f, S1 = 0.f, Q0 = 0.f, Q1 = 0.f;   // S here is S' = lr .* S
    #pragma unroll
    for (int c = 0; c < CHK; ++c){
      const float ec = __int_as_float(__builtin_amdgcn_readlane(__float_as_int(e_own), c));
      const float x0 = xr[c].x, x1 = xr[c].y;
      const float ex0 = ec * x0;
      const float ex1 = ec * x1;
      S0 = fmaf(lr0, ex0, S0);
      S1 = fmaf(lr1, ex1, S1);
      float pc = x0 * S0;
      pc = fmaf(x1, S1, pc);
      Q0 = fmaf(ex0, ex0, Q0);
      Q1 = fmaf(ex1, ex1, Q1);
      arr[c] = pc;
    }
    const float p = butterfly64(arr, lane);       // lane c: p_c = sum_j lr_j x_cj S_cj

    // (g) out_c = dot(mem, x_c) - B_LR*p_c = e_c + x_ci - B_LR*p_c
    outs[cur][lane*9 + w] = e_own + xci - B_LR * p;

    // (h) chunk-end state update (mem -= B_LR * S'; opt -= M_LR*lr*(1-lr)*Q)
    m0 = fmaf(-B_LR, S0, m0);
    m1 = fmaf(-B_LR, S1, m1);
    o0 = fmaf(-M_LR * lr0 * (1.f - lr0), Q0, o0);
    o1 = fmaf(-M_LR * lr1 * (1.f - lr1), Q1, o1);

    // (i) single barrier: drains glds (next chunk ready), publishes outs
    __syncthreads();
  }

  // epilogue: final chunk's outputs
  {
    const int c = tid >> 3, ww = tid & 7;
    Ob[(size_t)((NCHUNK-1)*CHK + c)*D + rg*8 + ww] = outs[(NCHUNK-1)&1][c*9 + ww];
  }
}

extern "C" void kernel_launch(void* const* d_in, const int* in_sizes, int n_in,
                              void* d_out, int out_size, void* d_ws, size_t ws_size,
                              hipStream_t stream) {
    const float* X  = (const float*)d_in[0];
    const float* im = (const float*)d_in[1];
    const float* io = (const float*)d_in[2];
    float* O        = (float*)d_out;
    hipLaunchKernelGGL(lfltm_fwd, dim3(256), dim3(512), 0, stream, X, im, io, O);
}